// Round 13
// baseline (362.415 us; speedup 1.0000x reference)
//
#include <hip/hip_runtime.h>
#include <hip/hip_bf16.h>

#define D_MODEL 1024
#define D_INNER 2048
#define D_STATE 16
#define D_CONV  4
#define DT_RANK 64
#define B_SZ    2
#define L_SEQ   1024
#define BL      (B_SZ * L_SEQ)          // 2048 rows
#define NPROJ   (DT_RANK + 2 * D_STATE) // 96

typedef __attribute__((ext_vector_type(8))) short bf16x8;
typedef __attribute__((ext_vector_type(4))) float floatx4;
typedef unsigned short ushort_t;

__device__ __forceinline__ void mfma_bf16(floatx4& acc, bf16x8 a, bf16x8 b) {
    asm volatile("v_mfma_f32_16x16x32_bf16 %0, %1, %2, %0"
                 : "+v"(acc) : "v"(a), "v"(b));
}

__device__ __forceinline__ void cvt_hilo(float f, ushort_t& hi, ushort_t& lo) {
    __hip_bfloat16 h = __float2bfloat16(f);
    hi = *(ushort_t*)&h;
    __hip_bfloat16 l = __float2bfloat16(f - __bfloat162float(h));
    lo = *(ushort_t*)&l;
}

__device__ __forceinline__ void cvt_store4(float4 v, ushort_t* hi, ushort_t* lo) {
    ushort4 h, l;
    cvt_hilo(v.x, h.x, l.x);
    cvt_hilo(v.y, h.y, l.y);
    cvt_hilo(v.z, h.z, l.z);
    cvt_hilo(v.w, h.w, l.w);
    *(ushort4*)hi = h;
    *(ushort4*)lo = l;
}

// ---- fused: fp32 -> bf16 hi/lo planes (wi, wo, x) + zero proj/out ---------
// Zeroing stays on the compute path (no SDMA memset) — required for correct
// ordering vs later kernel atomics inside the captured graph (R12 fix).
#define N4_WI 1048576
#define N4_WO 524288
#define N4_X  524288
#define Z4_PROJ (BL * NPROJ / 4)          // 49152 float4s
#define Z4_OUT  (BL * D_MODEL / 4)        // 524288 float4s
#define N4_TOT  (N4_WI + N4_WO + N4_X + Z4_PROJ + Z4_OUT)

__global__ __launch_bounds__(256) void cvt_static(
    const float* __restrict__ wi, ushort_t* wihi, ushort_t* wilo,
    const float* __restrict__ wo, ushort_t* wohi, ushort_t* wolo,
    const float* __restrict__ x,  ushort_t* xhi,  ushort_t* xlo,
    float* __restrict__ proj, float* __restrict__ out)
{
    int i = blockIdx.x * 256 + threadIdx.x;
    if (i >= N4_TOT) return;
    const float* src; ushort_t *dh, *dl;
    if (i < N4_WI)                 { src = wi; dh = wihi; dl = wilo; }
    else if ((i -= N4_WI) < N4_WO) { src = wo; dh = wohi; dl = wolo; }
    else if ((i -= N4_WO) < N4_X)  { src = x;  dh = xhi;  dl = xlo;  }
    else {
        i -= N4_X;
        float4 z = make_float4(0.f, 0.f, 0.f, 0.f);
        if (i < Z4_PROJ) ((float4*)proj)[i] = z;
        else             ((float4*)out)[i - Z4_PROJ] = z;
        return;
    }
    float4 v = ((const float4*)src)[i];
    cvt_store4(v, dh + i * 4, dl + i * 4);
}

// ---------------- pre-split bf16 MFMA GEMM ---------------------------------
// C[M,N] = A[M,K] @ B[N,K]^T from hi/lo bf16 planes (3-term split product).
// TM x TN tile, 256 threads = 4 waves (2x2), wave computes (TM/2)x(TN/2).
// LDS: 32 shorts/row, XOR-swizzled (group c of row r at c ^ ((r>>1)&3)):
// fragment reads hit all 32 banks exactly 2-way (free) [R10: conflicts -> 0].
// KSPLIT: >1 = K split across blockIdx.z, atomicAdd epilogue (C pre-zeroed)
template <int TM, int TN, int KSPLIT>
__global__ __launch_bounds__(256, 2) void gemm_pre(
    const ushort_t* __restrict__ Ahi, const ushort_t* __restrict__ Alo, int lda,
    const ushort_t* __restrict__ Bhi, const ushort_t* __restrict__ Blo, int ldb,
    float* __restrict__ C, int ldc, int K)
{
    constexpr int LDT = 32;
    constexpr int IT = TM / 32, JT = TN / 32;
    __shared__ __align__(16) ushort_t As[2][TM * LDT];
    __shared__ __align__(16) ushort_t Bs[2][TN * LDT];

    const int tid = threadIdx.x;
    const int bm = blockIdx.y * TM;
    const int bn = blockIdx.x * TN;
    const int kstart = (KSPLIT > 1) ? blockIdx.z * (K / KSPLIT) : 0;
    const int kend   = (KSPLIT > 1) ? kstart + K / KSPLIT : K;

    const int wave = tid >> 6;
    const int lane = tid & 63;
    const int wm = (wave >> 1) * (TM / 2);
    const int wn = (wave & 1) * (TN / 2);
    const int ml = lane & 15;
    const int q  = lane >> 4;

    floatx4 acc[IT][JT];
#pragma unroll
    for (int i = 0; i < IT; ++i)
#pragma unroll
        for (int j = 0; j < JT; ++j) acc[i][j] = (floatx4)0.f;

    for (int k0 = kstart; k0 < kend; k0 += 32) {
        __syncthreads();
#pragma unroll
        for (int ci = 0; ci < TM / 64; ++ci) {
            const int flat = tid + 256 * ci;
            const int r = flat >> 2, c = flat & 3;
            const int p = (c ^ ((r >> 1) & 3)) * 8;
            *(uint4*)&As[0][r * LDT + p] =
                *(const uint4*)(Ahi + (size_t)(bm + r) * lda + k0 + c * 8);
            *(uint4*)&As[1][r * LDT + p] =
                *(const uint4*)(Alo + (size_t)(bm + r) * lda + k0 + c * 8);
        }
#pragma unroll
        for (int ci = 0; ci < TN / 64; ++ci) {
            const int flat = tid + 256 * ci;
            const int r = flat >> 2, c = flat & 3;
            const int p = (c ^ ((r >> 1) & 3)) * 8;
            *(uint4*)&Bs[0][r * LDT + p] =
                *(const uint4*)(Bhi + (size_t)(bn + r) * ldb + k0 + c * 8);
            *(uint4*)&Bs[1][r * LDT + p] =
                *(const uint4*)(Blo + (size_t)(bn + r) * ldb + k0 + c * 8);
        }
        __syncthreads();

        bf16x8 ah[IT], al[IT], bh[JT], bl[JT];
#pragma unroll
        for (int i = 0; i < IT; ++i) {
            const int r = wm + i * 16 + ml;
            const int p = (q ^ ((r >> 1) & 3)) * 8;
            ah[i] = *(const bf16x8*)&As[0][r * LDT + p];
            al[i] = *(const bf16x8*)&As[1][r * LDT + p];
        }
#pragma unroll
        for (int j = 0; j < JT; ++j) {
            const int r = wn + j * 16 + ml;
            const int p = (q ^ ((r >> 1) & 3)) * 8;
            bh[j] = *(const bf16x8*)&Bs[0][r * LDT + p];
            bl[j] = *(const bf16x8*)&Bs[1][r * LDT + p];
        }
#pragma unroll
        for (int i = 0; i < IT; ++i)
#pragma unroll
            for (int j = 0; j < JT; ++j) {
                mfma_bf16(acc[i][j], ah[i], bh[j]);
                mfma_bf16(acc[i][j], ah[i], bl[j]);
                mfma_bf16(acc[i][j], al[i], bh[j]);
            }
    }

    asm volatile("s_nop 7\n\ts_nop 7\n\ts_nop 7" ::: "memory");

#pragma unroll
    for (int i = 0; i < IT; ++i)
#pragma unroll
        for (int j = 0; j < JT; ++j)
#pragma unroll
            for (int r = 0; r < 4; ++r) {
                const int row = bm + wm + i * 16 + q * 4 + r;
                const int col = bn + wn + j * 16 + ml;
                if (KSPLIT > 1)
                    atomicAdd(C + (size_t)row * ldc + col, acc[i][j][r]);
                else
                    C[(size_t)row * ldc + col] = acc[i][j][r];
            }
}

// ---------- dedicated fp32 delta kernel (K=64, epilogue-dominated) ---------
__global__ __launch_bounds__(256) void delta_kernel(
    const float* __restrict__ proj,   // [BL, 96]
    const float* __restrict__ Wd,     // [2048, 64]
    const float* __restrict__ bias,   // [2048]
    float* __restrict__ xz)           // out: cols 0..2047, ld 4096
{
    __shared__ float ps[16][65];
    const int d  = blockIdx.x * 256 + threadIdx.x;
    const int r0 = blockIdx.y * 16;

    {
        const int rr = threadIdx.x >> 4;
        const int cc = (threadIdx.x & 15) * 4;
        float4 v = *(const float4*)(proj + (size_t)(r0 + rr) * NPROJ + cc);
        ps[rr][cc + 0] = v.x; ps[rr][cc + 1] = v.y;
        ps[rr][cc + 2] = v.z; ps[rr][cc + 3] = v.w;
    }
    __syncthreads();

    float w[64];
#pragma unroll
    for (int c4 = 0; c4 < 16; ++c4) {
        float4 v = *(const float4*)(Wd + (size_t)d * 64 + c4 * 4);
        w[c4 * 4 + 0] = v.x; w[c4 * 4 + 1] = v.y;
        w[c4 * 4 + 2] = v.z; w[c4 * 4 + 3] = v.w;
    }
    const float bv = bias[d];

#pragma unroll
    for (int rr = 0; rr < 16; ++rr) {
        float acc = bv;
#pragma unroll
        for (int k = 0; k < 64; ++k) acc += ps[rr][k] * w[k];
        acc = (acc > 20.f) ? acc : log1pf(__expf(acc));
        xz[(size_t)(r0 + rr) * 4096 + d] = acc;
    }
}

// ------- fused depthwise-conv+SiLU + thin-N split-K GEMM for proj ----------
#define PKC 128   // K per block (16 k-splits -> 512 blocks)
#define PSC 64    // K sub-chunk staged in LDS

__global__ __launch_bounds__(256) void gemm_proj_conv(
    const float* __restrict__ xz,      // [BL,4096], x_br = cols 0..2047
    const float* __restrict__ conv_w,  // [2048,4]
    const float* __restrict__ conv_b,  // [2048]
    const float* __restrict__ Wp,      // [96,2048]
    float* __restrict__ proj,          // pre-zeroed (cvt_static)
    float* __restrict__ u_out)         // [BL,2048]
{
    __shared__ float us[PSC][65];
    __shared__ float wsh[PSC][100];

    const int tid = threadIdx.x;
    const int bm = blockIdx.y * 64;
    const int kbase0 = blockIdx.x * PKC;

    const int tx = tid & 15;
    const int ty = tid >> 4;

    float acc[4][6];
#pragma unroll
    for (int i = 0; i < 4; ++i)
#pragma unroll
        for (int j = 0; j < 6; ++j) acc[i][j] = 0.f;

    for (int sc = 0; sc < PKC / PSC; ++sc) {
        const int kb = kbase0 + sc * PSC;
        __syncthreads();
#pragma unroll
        for (int i = 0; i < 4; ++i) {
            const int flat = tid + 256 * i;
            const int r  = flat >> 4;
            const int kk = (flat & 15) * 4;
            const int k  = kb + kk;
            const int rr = bm + r;
            const int t  = rr & (L_SEQ - 1);
            const float* base = xz + (size_t)rr * 4096 + k;
            float4 x0 = *(const float4*)(base);
            float4 x1 = (t >= 1) ? *(const float4*)(base - 4096)  : make_float4(0,0,0,0);
            float4 x2 = (t >= 2) ? *(const float4*)(base - 8192)  : make_float4(0,0,0,0);
            float4 x3 = (t >= 3) ? *(const float4*)(base - 12288) : make_float4(0,0,0,0);
            float4 cb = *(const float4*)(conv_b + k);
            float4 w0 = ((const float4*)conv_w)[k + 0];
            float4 w1 = ((const float4*)conv_w)[k + 1];
            float4 w2 = ((const float4*)conv_w)[k + 2];
            float4 w3 = ((const float4*)conv_w)[k + 3];
            float4 uo;
            { float a = cb.x + w0.x*x3.x + w0.y*x2.x + w0.z*x1.x + w0.w*x0.x;
              uo.x = a / (1.f + __expf(-a)); }
            { float a = cb.y + w1.x*x3.y + w1.y*x2.y + w1.z*x1.y + w1.w*x0.y;
              uo.y = a / (1.f + __expf(-a)); }
            { float a = cb.z + w2.x*x3.z + w2.y*x2.z + w2.z*x1.z + w2.w*x0.z;
              uo.z = a / (1.f + __expf(-a)); }
            { float a = cb.w + w3.x*x3.w + w3.y*x2.w + w3.z*x1.w + w3.w*x0.w;
              uo.w = a / (1.f + __expf(-a)); }
            us[kk + 0][r] = uo.x;
            us[kk + 1][r] = uo.y;
            us[kk + 2][r] = uo.z;
            us[kk + 3][r] = uo.w;
            *(float4*)(u_out + (size_t)rr * D_INNER + k) = uo;
        }
#pragma unroll
        for (int i = 0; i < 6; ++i) {
            const int flat = tid + 256 * i;
            const int r = flat >> 4;
            const int k4 = flat & 15;
            float4 v = *(const float4*)(Wp + (size_t)r * D_INNER + kb + k4 * 4);
            wsh[k4*4+0][r] = v.x; wsh[k4*4+1][r] = v.y;
            wsh[k4*4+2][r] = v.z; wsh[k4*4+3][r] = v.w;
        }
        __syncthreads();

#pragma unroll 8
        for (int kk = 0; kk < PSC; ++kk) {
            float a[4], b[6];
#pragma unroll
            for (int i = 0; i < 4; ++i) a[i] = us[kk][ty * 4 + i];
#pragma unroll
            for (int j = 0; j < 6; ++j) b[j] = wsh[kk][tx + 16 * j];
#pragma unroll
            for (int i = 0; i < 4; ++i)
#pragma unroll
                for (int j = 0; j < 6; ++j) acc[i][j] += a[i] * b[j];
        }
    }

#pragma unroll
    for (int i = 0; i < 4; ++i)
#pragma unroll
        for (int j = 0; j < 6; ++j)
            atomicAdd(proj + (size_t)(bm + ty * 4 + i) * NPROJ + tx + 16 * j,
                      acc[i][j]);
}

// ---- chunked associative scan (template CSv; nc passed at runtime) --------
template <int CSv>
__global__ __launch_bounds__(256) void scan_phase_a(
    const float* __restrict__ xz,
    const float* __restrict__ u,
    const float* __restrict__ proj,
    const float* __restrict__ A_log,
    float* __restrict__ hloc,
    float* __restrict__ sumd,
    int nc)
{
    const int d = blockIdx.x * 256 + threadIdx.x;
    const int c = blockIdx.y;
    const int b = blockIdx.z;

    float a[D_STATE];
#pragma unroll
    for (int s = 0; s < D_STATE; ++s) a[s] = -__expf(A_log[d * D_STATE + s]);

    float h[D_STATE];
#pragma unroll
    for (int s = 0; s < D_STATE; ++s) h[s] = 0.f;
    float sd = 0.f;

    for (int t = c * CSv; t < (c + 1) * CSv; ++t) {
        const size_t bt = (size_t)b * L_SEQ + t;
        const float dv = xz[bt * (2 * D_INNER) + d];
        const float uv = u[bt * D_INNER + d];
        const float du = dv * uv;
        sd += dv;
        const float* pr = proj + bt * NPROJ;
#pragma unroll
        for (int s = 0; s < D_STATE; ++s)
            h[s] = __expf(dv * a[s]) * h[s] + du * pr[DT_RANK + s];
    }

    const size_t base = ((size_t)(b * nc + c) * D_STATE) * D_INNER + d;
#pragma unroll
    for (int s = 0; s < D_STATE; ++s) hloc[base + (size_t)s * D_INNER] = h[s];
    sumd[(size_t)(b * nc + c) * D_INNER + d] = sd;
}

__global__ __launch_bounds__(256) void scan_phase_b(
    const float* __restrict__ hloc,
    const float* __restrict__ sumd,
    const float* __restrict__ A_log,
    float* __restrict__ carry,
    int nc)
{
    const int d = blockIdx.x * 256 + threadIdx.x;
    const int b = blockIdx.y;

    float a[D_STATE];
#pragma unroll
    for (int s = 0; s < D_STATE; ++s) a[s] = -__expf(A_log[d * D_STATE + s]);

    float hc[D_STATE];
#pragma unroll
    for (int s = 0; s < D_STATE; ++s) {
        hc[s] = 0.f;
        carry[((size_t)(b * nc + 0) * D_STATE + s) * D_INNER + d] = 0.f;
    }

    for (int c = 1; c < nc; ++c) {
        const float sd = sumd[(size_t)(b * nc + c - 1) * D_INNER + d];
        const size_t pbase = ((size_t)(b * nc + c - 1) * D_STATE) * D_INNER + d;
        const size_t cbase = ((size_t)(b * nc + c) * D_STATE) * D_INNER + d;
#pragma unroll
        for (int s = 0; s < D_STATE; ++s) {
            const float P = __expf(a[s] * sd);
            hc[s] = P * hc[s] + hloc[pbase + (size_t)s * D_INNER];
            carry[cbase + (size_t)s * D_INNER] = hc[s];
        }
    }
}

template <int CSv>
__global__ __launch_bounds__(256) void scan_phase_c(
    const float* __restrict__ xz,
    const float* __restrict__ u,
    const float* __restrict__ proj,
    const float* __restrict__ A_log,
    const float* __restrict__ D_param,
    const float* __restrict__ carry,
    ushort_t* __restrict__ Yhi,
    ushort_t* __restrict__ Ylo,
    int nc)
{
    const int d = blockIdx.x * 256 + threadIdx.x;
    const int c = blockIdx.y;
    const int b = blockIdx.z;

    float a[D_STATE];
#pragma unroll
    for (int s = 0; s < D_STATE; ++s) a[s] = -__expf(A_log[d * D_STATE + s]);
    const float Dp = D_param[d];

    float h[D_STATE];
    const size_t cbase = ((size_t)(b * nc + c) * D_STATE) * D_INNER + d;
#pragma unroll
    for (int s = 0; s < D_STATE; ++s) h[s] = carry[cbase + (size_t)s * D_INNER];

    for (int t = c * CSv; t < (c + 1) * CSv; ++t) {
        const size_t bt = (size_t)b * L_SEQ + t;
        const float dv = xz[bt * (2 * D_INNER) + d];
        const float uv = u[bt * D_INNER + d];
        const float du = dv * uv;
        const float* pr = proj + bt * NPROJ;

        float acc = 0.f;
#pragma unroll
        for (int s = 0; s < D_STATE; ++s) {
            h[s] = __expf(dv * a[s]) * h[s] + du * pr[DT_RANK + s];
            acc += h[s] * pr[DT_RANK + D_STATE + s];
        }
        const float yv = acc + Dp * uv;

        const float zv = xz[bt * (2 * D_INNER) + D_INNER + d];
        const float gate = zv / (1.f + __expf(-zv));
        ushort_t hh, ll;
        cvt_hilo(yv * gate, hh, ll);
        Yhi[bt * D_INNER + d] = hh;
        Ylo[bt * D_INNER + d] = ll;
    }
}

extern "C" void kernel_launch(void* const* d_in, const int* in_sizes, int n_in,
                              void* d_out, int out_size, void* d_ws, size_t ws_size,
                              hipStream_t stream)
{
    const float* x         = (const float*)d_in[0];
    const float* in_proj_w = (const float*)d_in[1];
    const float* conv_w    = (const float*)d_in[2];
    const float* conv_b    = (const float*)d_in[3];
    const float* x_proj_w  = (const float*)d_in[4];
    const float* dt_proj_w = (const float*)d_in[5];
    const float* dt_proj_b = (const float*)d_in[6];
    const float* A_log     = (const float*)d_in[7];
    const float* D_param   = (const float*)d_in[8];
    const float* out_proj_w= (const float*)d_in[9];
    float* out = (float*)d_out;

    // Scan granularity: CS=16 (NC=64, 4 blocks/CU) needs 94.1 MB workspace;
    // fall back to the proven CS=32 (NC=32) layout if ws_size is smaller.
    const size_t fixed =
        (size_t)BL * 4096 * 4 +          // xz
        (size_t)BL * 2048 * 4 +          // u
        (size_t)BL * NPROJ * 4 +         // proj
        (size_t)(4096 + 2048) * 1024 * 2 * 2;  // Wi planes (16.78M) + Wo planes (8.39M)
    const size_t need64 = fixed + (size_t)B_SZ * 64 * D_INNER * 4
                                + (size_t)B_SZ * 64 * D_STATE * D_INNER * 4;
    const int nc = (ws_size >= need64) ? 64 : 32;
    const int cs = L_SEQ / nc;

    float* xz    = (float*)d_ws;              // [BL,4096] f32: x_br -> delta | z
    float* u     = xz    + (size_t)BL * 4096; // [BL,2048] f32
    float* proj  = u     + (size_t)BL * 2048; // [BL,96]   f32
    float* sumd  = proj  + (size_t)BL * NPROJ;
    float* carry = sumd  + (size_t)B_SZ * nc * D_INNER;
    ushort_t* Wihi = (ushort_t*)(carry + (size_t)B_SZ * nc * D_STATE * D_INNER);
    ushort_t* Wilo = Wihi + (size_t)4096 * 1024;
    ushort_t* Wohi = Wilo + (size_t)4096 * 1024;
    ushort_t* Wolo = Wohi + (size_t)1024 * 2048;
    // Aliases (disjoint lifetimes):
    ushort_t* Xhi  = (ushort_t*)carry;  // X planes dead before scan_b writes carry
    ushort_t* Xlo  = Xhi + (size_t)BL * D_MODEL;
    float*    hloc = (float*)Wihi;      // spans Wi planes; dead after scan_b
    ushort_t* Yhi  = Wihi;              // written by scan_c (after hloc is dead)
    ushort_t* Ylo  = Wilo;

    dim3 blk(256);

    // 0. fused: weight/x hi-lo conversion + zero proj/out (compute path)
    cvt_static<<<(N4_TOT + 255) / 256, blk, 0, stream>>>(
        in_proj_w, Wihi, Wilo, out_proj_w, Wohi, Wolo, x, Xhi, Xlo, proj, out);

    // 1. xz = x @ in_proj_w^T   (2048 x 4096 x 1024)
    gemm_pre<128, 128, 1><<<dim3(4096 / 128, BL / 128), blk, 0, stream>>>(
        Xhi, Xlo, D_MODEL, Wihi, Wilo, D_MODEL, xz, 2 * D_INNER, D_MODEL);

    // 2+3. fused conv+silu (u from xz) + proj = u @ x_proj_w^T [split-K atomics]
    gemm_proj_conv<<<dim3(D_INNER / PKC, BL / 64), blk, 0, stream>>>(
        xz, conv_w, conv_b, x_proj_w, proj, u);

    // 4. delta = softplus(proj[:,:64] @ dt_proj_w^T + b) -> xz cols 0..2047
    delta_kernel<<<dim3(D_INNER / 256, BL / 16), blk, 0, stream>>>(
        proj, dt_proj_w, dt_proj_b, xz);

    // 5. chunked SSM scan; phase C emits y as bf16 hi/lo planes
    if (cs == 16) {
        scan_phase_a<16><<<dim3(D_INNER / 256, nc, B_SZ), blk, 0, stream>>>(
            xz, u, proj, A_log, hloc, sumd, nc);
    } else {
        scan_phase_a<32><<<dim3(D_INNER / 256, nc, B_SZ), blk, 0, stream>>>(
            xz, u, proj, A_log, hloc, sumd, nc);
    }
    scan_phase_b<<<dim3(D_INNER / 256, B_SZ), blk, 0, stream>>>(
        hloc, sumd, A_log, carry, nc);
    if (cs == 16) {
        scan_phase_c<16><<<dim3(D_INNER / 256, nc, B_SZ), blk, 0, stream>>>(
            xz, u, proj, A_log, D_param, carry, Yhi, Ylo, nc);
    } else {
        scan_phase_c<32><<<dim3(D_INNER / 256, nc, B_SZ), blk, 0, stream>>>(
            xz, u, proj, A_log, D_param, carry, Yhi, Ylo, nc);
    }

    // 6. out = y @ out_proj_w^T (2048 x 1024 x 2048):
    //    TN=128 (48 MFMA/barrier like GEMM1), KSPLIT=4 -> 512 blocks = 2/CU
    gemm_pre<128, 128, 4><<<dim3(D_MODEL / 128, BL / 128, 4), blk, 0, stream>>>(
        Yhi, Ylo, D_INNER, Wohi, Wolo, D_INNER, out, D_MODEL, D_INNER);
}

// Round 14
// 314.757 us; speedup vs baseline: 1.1514x; 1.1514x over previous
//
#include <hip/hip_runtime.h>
#include <hip/hip_bf16.h>

#define D_MODEL 1024
#define D_INNER 2048
#define D_STATE 16
#define D_CONV  4
#define DT_RANK 64
#define B_SZ    2
#define L_SEQ   1024
#define BL      (B_SZ * L_SEQ)          // 2048 rows
#define NPROJ   (DT_RANK + 2 * D_STATE) // 96

typedef __attribute__((ext_vector_type(8))) short bf16x8;
typedef __attribute__((ext_vector_type(4))) float floatx4;
typedef unsigned short ushort_t;

__device__ __forceinline__ void mfma_bf16(floatx4& acc, bf16x8 a, bf16x8 b) {
    asm volatile("v_mfma_f32_16x16x32_bf16 %0, %1, %2, %0"
                 : "+v"(acc) : "v"(a), "v"(b));
}

__device__ __forceinline__ void cvt_hilo(float f, ushort_t& hi, ushort_t& lo) {
    __hip_bfloat16 h = __float2bfloat16(f);
    hi = *(ushort_t*)&h;
    __hip_bfloat16 l = __float2bfloat16(f - __bfloat162float(h));
    lo = *(ushort_t*)&l;
}

__device__ __forceinline__ void cvt_store4(float4 v, ushort_t* hi, ushort_t* lo) {
    ushort4 h, l;
    cvt_hilo(v.x, h.x, l.x);
    cvt_hilo(v.y, h.y, l.y);
    cvt_hilo(v.z, h.z, l.z);
    cvt_hilo(v.w, h.w, l.w);
    *(ushort4*)hi = h;
    *(ushort4*)lo = l;
}

// ---- fused: fp32 -> bf16 hi/lo planes (wi, wo, x) + zero proj/out ---------
// Zeroing stays on the compute path (no SDMA memset) — required for correct
// ordering vs later kernel atomics inside the captured graph (R12 fix).
#define N4_WI 1048576
#define N4_WO 524288
#define N4_X  524288
#define Z4_PROJ (BL * NPROJ / 4)          // 49152 float4s
#define Z4_OUT  (BL * D_MODEL / 4)        // 524288 float4s
#define N4_TOT  (N4_WI + N4_WO + N4_X + Z4_PROJ + Z4_OUT)

__global__ __launch_bounds__(256) void cvt_static(
    const float* __restrict__ wi, ushort_t* wihi, ushort_t* wilo,
    const float* __restrict__ wo, ushort_t* wohi, ushort_t* wolo,
    const float* __restrict__ x,  ushort_t* xhi,  ushort_t* xlo,
    float* __restrict__ proj, float* __restrict__ out)
{
    int i = blockIdx.x * 256 + threadIdx.x;
    if (i >= N4_TOT) return;
    const float* src; ushort_t *dh, *dl;
    if (i < N4_WI)                 { src = wi; dh = wihi; dl = wilo; }
    else if ((i -= N4_WI) < N4_WO) { src = wo; dh = wohi; dl = wolo; }
    else if ((i -= N4_WO) < N4_X)  { src = x;  dh = xhi;  dl = xlo;  }
    else {
        i -= N4_X;
        float4 z = make_float4(0.f, 0.f, 0.f, 0.f);
        if (i < Z4_PROJ) ((float4*)proj)[i] = z;
        else             ((float4*)out)[i - Z4_PROJ] = z;
        return;
    }
    float4 v = ((const float4*)src)[i];
    cvt_store4(v, dh + i * 4, dl + i * 4);
}

// ---------------- pre-split bf16 MFMA GEMM ---------------------------------
// C[M,N] = A[M,K] @ B[N,K]^T from hi/lo bf16 planes (3-term split product).
// TM x TN tile, 256 threads = 4 waves (2x2), wave computes (TM/2)x(TN/2).
// LDS: 32 shorts/row, XOR-swizzled (group c of row r at c ^ ((r>>1)&3)):
// fragment reads hit all 32 banks exactly 2-way (free) [R10: conflicts -> 0].
// KSPLIT: >1 = K split across blockIdx.z, atomicAdd epilogue (C pre-zeroed)
template <int TM, int TN, int KSPLIT>
__global__ __launch_bounds__(256, 2) void gemm_pre(
    const ushort_t* __restrict__ Ahi, const ushort_t* __restrict__ Alo, int lda,
    const ushort_t* __restrict__ Bhi, const ushort_t* __restrict__ Blo, int ldb,
    float* __restrict__ C, int ldc, int K)
{
    constexpr int LDT = 32;
    constexpr int IT = TM / 32, JT = TN / 32;
    __shared__ __align__(16) ushort_t As[2][TM * LDT];
    __shared__ __align__(16) ushort_t Bs[2][TN * LDT];

    const int tid = threadIdx.x;
    const int bm = blockIdx.y * TM;
    const int bn = blockIdx.x * TN;
    const int kstart = (KSPLIT > 1) ? blockIdx.z * (K / KSPLIT) : 0;
    const int kend   = (KSPLIT > 1) ? kstart + K / KSPLIT : K;

    const int wave = tid >> 6;
    const int lane = tid & 63;
    const int wm = (wave >> 1) * (TM / 2);
    const int wn = (wave & 1) * (TN / 2);
    const int ml = lane & 15;
    const int q  = lane >> 4;

    floatx4 acc[IT][JT];
#pragma unroll
    for (int i = 0; i < IT; ++i)
#pragma unroll
        for (int j = 0; j < JT; ++j) acc[i][j] = (floatx4)0.f;

    for (int k0 = kstart; k0 < kend; k0 += 32) {
        __syncthreads();
#pragma unroll
        for (int ci = 0; ci < TM / 64; ++ci) {
            const int flat = tid + 256 * ci;
            const int r = flat >> 2, c = flat & 3;
            const int p = (c ^ ((r >> 1) & 3)) * 8;
            *(uint4*)&As[0][r * LDT + p] =
                *(const uint4*)(Ahi + (size_t)(bm + r) * lda + k0 + c * 8);
            *(uint4*)&As[1][r * LDT + p] =
                *(const uint4*)(Alo + (size_t)(bm + r) * lda + k0 + c * 8);
        }
#pragma unroll
        for (int ci = 0; ci < TN / 64; ++ci) {
            const int flat = tid + 256 * ci;
            const int r = flat >> 2, c = flat & 3;
            const int p = (c ^ ((r >> 1) & 3)) * 8;
            *(uint4*)&Bs[0][r * LDT + p] =
                *(const uint4*)(Bhi + (size_t)(bn + r) * ldb + k0 + c * 8);
            *(uint4*)&Bs[1][r * LDT + p] =
                *(const uint4*)(Blo + (size_t)(bn + r) * ldb + k0 + c * 8);
        }
        __syncthreads();

        bf16x8 ah[IT], al[IT], bh[JT], bl[JT];
#pragma unroll
        for (int i = 0; i < IT; ++i) {
            const int r = wm + i * 16 + ml;
            const int p = (q ^ ((r >> 1) & 3)) * 8;
            ah[i] = *(const bf16x8*)&As[0][r * LDT + p];
            al[i] = *(const bf16x8*)&As[1][r * LDT + p];
        }
#pragma unroll
        for (int j = 0; j < JT; ++j) {
            const int r = wn + j * 16 + ml;
            const int p = (q ^ ((r >> 1) & 3)) * 8;
            bh[j] = *(const bf16x8*)&Bs[0][r * LDT + p];
            bl[j] = *(const bf16x8*)&Bs[1][r * LDT + p];
        }
#pragma unroll
        for (int i = 0; i < IT; ++i)
#pragma unroll
            for (int j = 0; j < JT; ++j) {
                mfma_bf16(acc[i][j], ah[i], bh[j]);
                mfma_bf16(acc[i][j], ah[i], bl[j]);
                mfma_bf16(acc[i][j], al[i], bh[j]);
            }
    }

    asm volatile("s_nop 7\n\ts_nop 7\n\ts_nop 7" ::: "memory");

#pragma unroll
    for (int i = 0; i < IT; ++i)
#pragma unroll
        for (int j = 0; j < JT; ++j)
#pragma unroll
            for (int r = 0; r < 4; ++r) {
                const int row = bm + wm + i * 16 + q * 4 + r;
                const int col = bn + wn + j * 16 + ml;
                if (KSPLIT > 1)
                    atomicAdd(C + (size_t)row * ldc + col, acc[i][j][r]);
                else
                    C[(size_t)row * ldc + col] = acc[i][j][r];
            }
}

// ---------- dedicated fp32 delta kernel (K=64, epilogue-dominated) ---------
__global__ __launch_bounds__(256) void delta_kernel(
    const float* __restrict__ proj,   // [BL, 96]
    const float* __restrict__ Wd,     // [2048, 64]
    const float* __restrict__ bias,   // [2048]
    float* __restrict__ xz)           // out: cols 0..2047, ld 4096
{
    __shared__ float ps[16][65];
    const int d  = blockIdx.x * 256 + threadIdx.x;
    const int r0 = blockIdx.y * 16;

    {
        const int rr = threadIdx.x >> 4;
        const int cc = (threadIdx.x & 15) * 4;
        float4 v = *(const float4*)(proj + (size_t)(r0 + rr) * NPROJ + cc);
        ps[rr][cc + 0] = v.x; ps[rr][cc + 1] = v.y;
        ps[rr][cc + 2] = v.z; ps[rr][cc + 3] = v.w;
    }
    __syncthreads();

    float w[64];
#pragma unroll
    for (int c4 = 0; c4 < 16; ++c4) {
        float4 v = *(const float4*)(Wd + (size_t)d * 64 + c4 * 4);
        w[c4 * 4 + 0] = v.x; w[c4 * 4 + 1] = v.y;
        w[c4 * 4 + 2] = v.z; w[c4 * 4 + 3] = v.w;
    }
    const float bv = bias[d];

#pragma unroll
    for (int rr = 0; rr < 16; ++rr) {
        float acc = bv;
#pragma unroll
        for (int k = 0; k < 64; ++k) acc += ps[rr][k] * w[k];
        acc = (acc > 20.f) ? acc : log1pf(__expf(acc));
        xz[(size_t)(r0 + rr) * 4096 + d] = acc;
    }
}

// ------- fused depthwise-conv+SiLU + thin-N split-K GEMM for proj ----------
#define PKC 128   // K per block (16 k-splits -> 512 blocks)
#define PSC 64    // K sub-chunk staged in LDS

__global__ __launch_bounds__(256) void gemm_proj_conv(
    const float* __restrict__ xz,      // [BL,4096], x_br = cols 0..2047
    const float* __restrict__ conv_w,  // [2048,4]
    const float* __restrict__ conv_b,  // [2048]
    const float* __restrict__ Wp,      // [96,2048]
    float* __restrict__ proj,          // pre-zeroed (cvt_static)
    float* __restrict__ u_out)         // [BL,2048]
{
    __shared__ float us[PSC][65];
    __shared__ float wsh[PSC][100];

    const int tid = threadIdx.x;
    const int bm = blockIdx.y * 64;
    const int kbase0 = blockIdx.x * PKC;

    const int tx = tid & 15;
    const int ty = tid >> 4;

    float acc[4][6];
#pragma unroll
    for (int i = 0; i < 4; ++i)
#pragma unroll
        for (int j = 0; j < 6; ++j) acc[i][j] = 0.f;

    for (int sc = 0; sc < PKC / PSC; ++sc) {
        const int kb = kbase0 + sc * PSC;
        __syncthreads();
#pragma unroll
        for (int i = 0; i < 4; ++i) {
            const int flat = tid + 256 * i;
            const int r  = flat >> 4;
            const int kk = (flat & 15) * 4;
            const int k  = kb + kk;
            const int rr = bm + r;
            const int t  = rr & (L_SEQ - 1);
            const float* base = xz + (size_t)rr * 4096 + k;
            float4 x0 = *(const float4*)(base);
            float4 x1 = (t >= 1) ? *(const float4*)(base - 4096)  : make_float4(0,0,0,0);
            float4 x2 = (t >= 2) ? *(const float4*)(base - 8192)  : make_float4(0,0,0,0);
            float4 x3 = (t >= 3) ? *(const float4*)(base - 12288) : make_float4(0,0,0,0);
            float4 cb = *(const float4*)(conv_b + k);
            float4 w0 = ((const float4*)conv_w)[k + 0];
            float4 w1 = ((const float4*)conv_w)[k + 1];
            float4 w2 = ((const float4*)conv_w)[k + 2];
            float4 w3 = ((const float4*)conv_w)[k + 3];
            float4 uo;
            { float a = cb.x + w0.x*x3.x + w0.y*x2.x + w0.z*x1.x + w0.w*x0.x;
              uo.x = a / (1.f + __expf(-a)); }
            { float a = cb.y + w1.x*x3.y + w1.y*x2.y + w1.z*x1.y + w1.w*x0.y;
              uo.y = a / (1.f + __expf(-a)); }
            { float a = cb.z + w2.x*x3.z + w2.y*x2.z + w2.z*x1.z + w2.w*x0.z;
              uo.z = a / (1.f + __expf(-a)); }
            { float a = cb.w + w3.x*x3.w + w3.y*x2.w + w3.z*x1.w + w3.w*x0.w;
              uo.w = a / (1.f + __expf(-a)); }
            us[kk + 0][r] = uo.x;
            us[kk + 1][r] = uo.y;
            us[kk + 2][r] = uo.z;
            us[kk + 3][r] = uo.w;
            *(float4*)(u_out + (size_t)rr * D_INNER + k) = uo;
        }
#pragma unroll
        for (int i = 0; i < 6; ++i) {
            const int flat = tid + 256 * i;
            const int r = flat >> 4;
            const int k4 = flat & 15;
            float4 v = *(const float4*)(Wp + (size_t)r * D_INNER + kb + k4 * 4);
            wsh[k4*4+0][r] = v.x; wsh[k4*4+1][r] = v.y;
            wsh[k4*4+2][r] = v.z; wsh[k4*4+3][r] = v.w;
        }
        __syncthreads();

#pragma unroll 8
        for (int kk = 0; kk < PSC; ++kk) {
            float a[4], b[6];
#pragma unroll
            for (int i = 0; i < 4; ++i) a[i] = us[kk][ty * 4 + i];
#pragma unroll
            for (int j = 0; j < 6; ++j) b[j] = wsh[kk][tx + 16 * j];
#pragma unroll
            for (int i = 0; i < 4; ++i)
#pragma unroll
                for (int j = 0; j < 6; ++j) acc[i][j] += a[i] * b[j];
        }
    }

#pragma unroll
    for (int i = 0; i < 4; ++i)
#pragma unroll
        for (int j = 0; j < 6; ++j)
            atomicAdd(proj + (size_t)(bm + ty * 4 + i) * NPROJ + tx + 16 * j,
                      acc[i][j]);
}

// ---- chunked associative scan (template CSv; nc passed at runtime) --------
template <int CSv>
__global__ __launch_bounds__(256) void scan_phase_a(
    const float* __restrict__ xz,
    const float* __restrict__ u,
    const float* __restrict__ proj,
    const float* __restrict__ A_log,
    float* __restrict__ hloc,
    float* __restrict__ sumd,
    int nc)
{
    const int d = blockIdx.x * 256 + threadIdx.x;
    const int c = blockIdx.y;
    const int b = blockIdx.z;

    float a[D_STATE];
#pragma unroll
    for (int s = 0; s < D_STATE; ++s) a[s] = -__expf(A_log[d * D_STATE + s]);

    float h[D_STATE];
#pragma unroll
    for (int s = 0; s < D_STATE; ++s) h[s] = 0.f;
    float sd = 0.f;

    for (int t = c * CSv; t < (c + 1) * CSv; ++t) {
        const size_t bt = (size_t)b * L_SEQ + t;
        const float dv = xz[bt * (2 * D_INNER) + d];
        const float uv = u[bt * D_INNER + d];
        const float du = dv * uv;
        sd += dv;
        const float* pr = proj + bt * NPROJ;
#pragma unroll
        for (int s = 0; s < D_STATE; ++s)
            h[s] = __expf(dv * a[s]) * h[s] + du * pr[DT_RANK + s];
    }

    const size_t base = ((size_t)(b * nc + c) * D_STATE) * D_INNER + d;
#pragma unroll
    for (int s = 0; s < D_STATE; ++s) hloc[base + (size_t)s * D_INNER] = h[s];
    sumd[(size_t)(b * nc + c) * D_INNER + d] = sd;
}

// Phase B, parallel over (b, d, s): one thread per state-channel pair.
// 65536 threads = 256 blocks; d is lane-fastest -> hloc/carry coalesced.
// Per-thread serial chunk loop; load chain independent of hc recurrence.
__global__ __launch_bounds__(256) void scan_phase_b(
    const float* __restrict__ hloc,
    const float* __restrict__ sumd,
    const float* __restrict__ A_log,
    float* __restrict__ carry,
    int nc)
{
    const int g = blockIdx.x * 256 + threadIdx.x;  // [0, 65536)
    const int d = g & (D_INNER - 1);
    const int s = (g >> 11) & (D_STATE - 1);
    const int b = g >> 15;

    const float a_s = -__expf(A_log[d * D_STATE + s]);

    float hc = 0.f;
    carry[((size_t)(b * nc + 0) * D_STATE + s) * D_INNER + d] = 0.f;

    for (int c = 1; c < nc; ++c) {
        const float sd = sumd[(size_t)(b * nc + c - 1) * D_INNER + d];
        const float hl = hloc[((size_t)(b * nc + c - 1) * D_STATE + s) * D_INNER + d];
        hc = __expf(a_s * sd) * hc + hl;
        carry[((size_t)(b * nc + c) * D_STATE + s) * D_INNER + d] = hc;
    }
}

template <int CSv>
__global__ __launch_bounds__(256) void scan_phase_c(
    const float* __restrict__ xz,
    const float* __restrict__ u,
    const float* __restrict__ proj,
    const float* __restrict__ A_log,
    const float* __restrict__ D_param,
    const float* __restrict__ carry,
    ushort_t* __restrict__ Yhi,
    ushort_t* __restrict__ Ylo,
    int nc)
{
    const int d = blockIdx.x * 256 + threadIdx.x;
    const int c = blockIdx.y;
    const int b = blockIdx.z;

    float a[D_STATE];
#pragma unroll
    for (int s = 0; s < D_STATE; ++s) a[s] = -__expf(A_log[d * D_STATE + s]);
    const float Dp = D_param[d];

    float h[D_STATE];
    const size_t cbase = ((size_t)(b * nc + c) * D_STATE) * D_INNER + d;
#pragma unroll
    for (int s = 0; s < D_STATE; ++s) h[s] = carry[cbase + (size_t)s * D_INNER];

    for (int t = c * CSv; t < (c + 1) * CSv; ++t) {
        const size_t bt = (size_t)b * L_SEQ + t;
        const float dv = xz[bt * (2 * D_INNER) + d];
        const float uv = u[bt * D_INNER + d];
        const float du = dv * uv;
        const float* pr = proj + bt * NPROJ;

        float acc = 0.f;
#pragma unroll
        for (int s = 0; s < D_STATE; ++s) {
            h[s] = __expf(dv * a[s]) * h[s] + du * pr[DT_RANK + s];
            acc += h[s] * pr[DT_RANK + D_STATE + s];
        }
        const float yv = acc + Dp * uv;

        const float zv = xz[bt * (2 * D_INNER) + D_INNER + d];
        const float gate = zv / (1.f + __expf(-zv));
        ushort_t hh, ll;
        cvt_hilo(yv * gate, hh, ll);
        Yhi[bt * D_INNER + d] = hh;
        Ylo[bt * D_INNER + d] = ll;
    }
}

extern "C" void kernel_launch(void* const* d_in, const int* in_sizes, int n_in,
                              void* d_out, int out_size, void* d_ws, size_t ws_size,
                              hipStream_t stream)
{
    const float* x         = (const float*)d_in[0];
    const float* in_proj_w = (const float*)d_in[1];
    const float* conv_w    = (const float*)d_in[2];
    const float* conv_b    = (const float*)d_in[3];
    const float* x_proj_w  = (const float*)d_in[4];
    const float* dt_proj_w = (const float*)d_in[5];
    const float* dt_proj_b = (const float*)d_in[6];
    const float* A_log     = (const float*)d_in[7];
    const float* D_param   = (const float*)d_in[8];
    const float* out_proj_w= (const float*)d_in[9];
    float* out = (float*)d_out;

    // Scan granularity: CS=16 (NC=64, 4 blocks/CU in A/C) needs 94.1 MB;
    // fall back to CS=32 (NC=32) if ws_size is smaller.
    const size_t fixed =
        (size_t)BL * 4096 * 4 +          // xz
        (size_t)BL * 2048 * 4 +          // u
        (size_t)BL * NPROJ * 4 +         // proj
        (size_t)(4096 + 2048) * 1024 * 2 * 2;  // Wi + Wo planes
    const size_t need64 = fixed + (size_t)B_SZ * 64 * D_INNER * 4
                                + (size_t)B_SZ * 64 * D_STATE * D_INNER * 4;
    const int nc = (ws_size >= need64) ? 64 : 32;
    const int cs = L_SEQ / nc;

    float* xz    = (float*)d_ws;              // [BL,4096] f32: x_br -> delta | z
    float* u     = xz    + (size_t)BL * 4096; // [BL,2048] f32
    float* proj  = u     + (size_t)BL * 2048; // [BL,96]   f32
    float* sumd  = proj  + (size_t)BL * NPROJ;
    float* carry = sumd  + (size_t)B_SZ * nc * D_INNER;
    ushort_t* Wihi = (ushort_t*)(carry + (size_t)B_SZ * nc * D_STATE * D_INNER);
    ushort_t* Wilo = Wihi + (size_t)4096 * 1024;
    ushort_t* Wohi = Wilo + (size_t)4096 * 1024;
    ushort_t* Wolo = Wohi + (size_t)1024 * 2048;
    // Aliases (disjoint lifetimes):
    ushort_t* Xhi  = (ushort_t*)carry;  // X planes dead before scan_b writes carry
    ushort_t* Xlo  = Xhi + (size_t)BL * D_MODEL;
    float*    hloc = (float*)Wihi;      // spans Wi planes; dead after scan_b
    ushort_t* Yhi  = Wihi;              // written by scan_c (after hloc is dead)
    ushort_t* Ylo  = Wilo;

    dim3 blk(256);

    // 0. fused: weight/x hi-lo conversion + zero proj/out (compute path)
    cvt_static<<<(N4_TOT + 255) / 256, blk, 0, stream>>>(
        in_proj_w, Wihi, Wilo, out_proj_w, Wohi, Wolo, x, Xhi, Xlo, proj, out);

    // 1. xz = x @ in_proj_w^T   (2048 x 4096 x 1024)
    gemm_pre<128, 128, 1><<<dim3(4096 / 128, BL / 128), blk, 0, stream>>>(
        Xhi, Xlo, D_MODEL, Wihi, Wilo, D_MODEL, xz, 2 * D_INNER, D_MODEL);

    // 2+3. fused conv+silu (u from xz) + proj = u @ x_proj_w^T [split-K atomics]
    gemm_proj_conv<<<dim3(D_INNER / PKC, BL / 64), blk, 0, stream>>>(
        xz, conv_w, conv_b, x_proj_w, proj, u);

    // 4. delta = softplus(proj[:,:64] @ dt_proj_w^T + b) -> xz cols 0..2047
    delta_kernel<<<dim3(D_INNER / 256, BL / 16), blk, 0, stream>>>(
        proj, dt_proj_w, dt_proj_b, xz);

    // 5. chunked SSM scan; phase B parallel over (b,d,s) = 256 blocks
    if (cs == 16) {
        scan_phase_a<16><<<dim3(D_INNER / 256, nc, B_SZ), blk, 0, stream>>>(
            xz, u, proj, A_log, hloc, sumd, nc);
    } else {
        scan_phase_a<32><<<dim3(D_INNER / 256, nc, B_SZ), blk, 0, stream>>>(
            xz, u, proj, A_log, hloc, sumd, nc);
    }
    scan_phase_b<<<dim3((B_SZ * D_INNER * D_STATE) / 256), blk, 0, stream>>>(
        hloc, sumd, A_log, carry, nc);
    if (cs == 16) {
        scan_phase_c<16><<<dim3(D_INNER / 256, nc, B_SZ), blk, 0, stream>>>(
            xz, u, proj, A_log, D_param, carry, Yhi, Ylo, nc);
    } else {
        scan_phase_c<32><<<dim3(D_INNER / 256, nc, B_SZ), blk, 0, stream>>>(
            xz, u, proj, A_log, D_param, carry, Yhi, Ylo, nc);
    }

    // 6. out = y @ out_proj_w^T (2048 x 1024 x 2048):
    //    TN=128 (48 MFMA/barrier like GEMM1), KSPLIT=4 -> 512 blocks = 2/CU
    gemm_pre<128, 128, 4><<<dim3(D_MODEL / 128, BL / 128, 4), blk, 0, stream>>>(
        Yhi, Ylo, D_INNER, Wohi, Wolo, D_INNER, out, D_MODEL, D_INNER);
}